// Round 18
// baseline (130.413 us; speedup 1.0000x reference)
//
#include <hip/hip_runtime.h>

#define EPSF 1e-6f
#define Bsz 2
#define Tn  512
#define En  1024
#define Hn  256
#define Mtot (Bsz * Tn)          // 1024 rows
#define REP 8                    // measurement-round repeat factor (idempotent)
typedef unsigned short us_t;
typedef unsigned int   u32_t;

typedef __attribute__((ext_vector_type(8))) __fp16 f16x8;
typedef __attribute__((ext_vector_type(2))) __fp16 h2_t;
typedef __attribute__((ext_vector_type(8))) short  short8;   // raw 16B container
typedef __attribute__((ext_vector_type(4))) float  f32x4;
#define MFMA16(a, b, c) __builtin_amdgcn_mfma_f32_16x16x32_f16((a), (b), (c), 0, 0, 0)

// async global->LDS, 16B per lane, HW appends lane*16 to the uniform LDS base
#define GLOAD_LDS16(g, l) __builtin_amdgcn_global_load_lds( \
  (const __attribute__((address_space(1))) unsigned int*)(g), \
  (__attribute__((address_space(3))) unsigned int*)(l), 16, 0, 0)

// ---------------------------------------------------------------------------
__device__ __forceinline__ us_t f2h(float f) {
  __fp16 h = (__fp16)f;                       // RNE
  return __builtin_bit_cast(us_t, h);
}
__device__ __forceinline__ float h2f(us_t u) {
  return (float)__builtin_bit_cast(__fp16, u);
}
__device__ __forceinline__ uint2 pack4h(float a, float b, float c, float d) {
  uint2 r;
  r.x = (u32_t)f2h(a) | ((u32_t)f2h(b) << 16);
  r.y = (u32_t)f2h(c) | ((u32_t)f2h(d) << 16);
  return r;
}
__device__ __forceinline__ float block_reduce_sum_256(float v, float* smem) {
  #pragma unroll
  for (int off = 32; off > 0; off >>= 1) v += __shfl_down(v, off, 64);
  const int wave = threadIdx.x >> 6;
  if ((threadIdx.x & 63) == 0) smem[wave] = v;
  __syncthreads();
  float s = smem[0] + smem[1] + smem[2] + smem[3];
  __syncthreads();
  return s;
}

// ---------------------------------------------------------------------------
// K0 prep (x REP): blocks 0..255: cast 4 x-rows + rowscale (XCD remap).
//                  blocks 256..1023: transpose+cast one 32x32 w-tile.
// ---------------------------------------------------------------------------
__global__ __launch_bounds__(256) void k_prep(
    const float* __restrict__ x,
    const float* __restrict__ w1, const float* __restrict__ w2,
    const float* __restrict__ w3,
    us_t* __restrict__ xb, float* __restrict__ rs,
    us_t* __restrict__ w1t, us_t* __restrict__ w2t, us_t* __restrict__ w3t)
{
  const int b = blockIdx.x, t = threadIdx.x;

  if (b < 256) {
    const int wid = t >> 6, lane = t & 63;
    const int q   = b >> 3;
    const int mt  = (b & 7) + 8 * (q & 7);
    const int row = 16 * mt + 4 * (q >> 3) + wid;
    for (int rep = 0; rep < REP; ++rep) {
      const float4* xp = (const float4*)(x + (size_t)row * En);
      float4 v[4];
      #pragma unroll
      for (int i = 0; i < 4; ++i) v[i] = xp[lane + 64 * i];
      float ss = 0.f;
      #pragma unroll
      for (int i = 0; i < 4; ++i)
        ss += v[i].x*v[i].x + v[i].y*v[i].y + v[i].z*v[i].z + v[i].w*v[i].w;
      #pragma unroll
      for (int off = 32; off > 0; off >>= 1) ss += __shfl_xor(ss, off, 64);
      if (lane == 0) rs[row] = rsqrtf(ss * (1.0f / En) + EPSF);
      uint2* xo = (uint2*)(xb + (size_t)row * En);
      #pragma unroll
      for (int i = 0; i < 4; ++i)
        xo[lane + 64 * i] = pack4h(v[i].x, v[i].y, v[i].z, v[i].w);
    }
    return;
  }

  __shared__ float ts[32][33];
  const int i = b - 256;
  const float* src; us_t* dst; int R, C, tr, tc;
  if (i < 256)      { src = w1; dst = w1t; R = 1024; C = 256;  tr = i >> 3;  tc = i & 7; }
  else if (i < 512) { int k = i - 256; src = w2; dst = w2t; R = 1024; C = 256; tr = k >> 3; tc = k & 7; }
  else              { int k = i - 512; src = w3; dst = w3t; R = 256; C = 1024; tr = k >> 5; tc = k & 31; }

  const int r = t >> 3, c4 = (t & 7) * 4;
  for (int rep = 0; rep < REP; ++rep) {
    float4 v = *(const float4*)(src + (size_t)(tr * 32 + r) * C + tc * 32 + c4);
    ts[r][c4 + 0] = v.x; ts[r][c4 + 1] = v.y; ts[r][c4 + 2] = v.z; ts[r][c4 + 3] = v.w;
    __syncthreads();
    float o0 = ts[c4 + 0][r], o1 = ts[c4 + 1][r], o2 = ts[c4 + 2][r], o3 = ts[c4 + 3][r];
    *(uint2*)(dst + (size_t)(tc * 32 + r) * R + tr * 32 + c4) = pack4h(o0, o1, o2, o3);
    __syncthreads();
  }
}

// ---------------------------------------------------------------------------
// K1 gemm (x REP): R17 body — 2048 blocks, 16x16 tile, split-K x4,
// async global_load_lds B staging with pre-swizzled source.
// ---------------------------------------------------------------------------
__global__ __launch_bounds__(256, 4) void k_gemm(
    const us_t* __restrict__ xb,
    const us_t* __restrict__ w1t, const us_t* __restrict__ w2t,
    float* __restrict__ Praw)
{
  __shared__ us_t Bs[4][16][256];      // 32 KB
  __shared__ float cmb[4][16][16];     // 4 KB

  const int blk = blockIdx.x;
  const int mt = blk & 63, nt = blk >> 6;
  const int m0 = mt * 16, n0 = nt * 16;
  const int t = threadIdx.x;
  const int wid = t >> 6, lane = t & 63;
  const int lg = lane >> 4, lr = lane & 15;
  const int k0 = wid * 256;

  const us_t* ap = xb + (size_t)(m0 + lr) * En + k0 + lg * 8;
  const us_t* bbase = (n0 < Hn) ? (w1t + (size_t)n0 * En)
                                : (w2t + (size_t)(n0 - Hn) * En);

  for (int rep = 0; rep < REP; ++rep) {
    f16x8 a[8];
    #pragma unroll
    for (int s = 0; s < 8; ++s) a[s] = *(const f16x8*)(ap + s * 32);

    #pragma unroll
    for (int i = 0; i < 8; ++i) {
      const int r   = 2 * i + (lane >> 5);
      const int c2b = ((lane & 31) * 16) ^ ((r & 7) << 4);
      const us_t* g = bbase + (size_t)r * En + k0 + (c2b >> 1);
      GLOAD_LDS16(g, &Bs[wid][2 * i][0]);
    }
    __syncthreads();

    f32x4 acc = {0.f,0.f,0.f,0.f};
    const us_t* bs = &Bs[wid][0][0];
    #pragma unroll
    for (int s = 0; s < 8; ++s) {
      const int c2 = (lg * 16 + s * 64) ^ ((lr & 7) << 4);
      f16x8 b = *(const f16x8*)(bs + lr * 256 + (c2 >> 1));
      acc = MFMA16(a[s], b, acc);
    }

    #pragma unroll
    for (int i = 0; i < 4; ++i)
      cmb[wid][lg * 4 + i][lr] = acc[i];
    __syncthreads();

    const int row = t >> 4, col = t & 15;
    float s2 = cmb[0][row][col] + cmb[1][row][col]
             + cmb[2][row][col] + cmb[3][row][col];
    Praw[(size_t)(m0 + row) * 512 + n0 + col] = s2;
    __syncthreads();
  }
}

// ---------------------------------------------------------------------------
// K2 norm (x REP): b-half only.  256 blocks, wave-per-row;
// LDS transpose-gather -> BmT[h][t] f16.
// ---------------------------------------------------------------------------
__global__ __launch_bounds__(256) void k_norm(
    const float* __restrict__ Praw, const float* __restrict__ rs,
    const float* __restrict__ b2, us_t* __restrict__ BmT)
{
  const int blk = blockIdx.x, t = threadIdx.x;
  const int wid = t >> 6, lane = t & 63;
  const int h0 = lane * 4;

  __shared__ us_t ls[4][256];
  const int mt = blk & 63, sub = blk >> 6;
  const int r0 = 16 * mt + 4 * sub;
  const int r  = r0 + wid;

  for (int rep = 0; rep < REP; ++rep) {
    float4 d = *(const float4*)(Praw + (size_t)r * 512 + Hn + h0);
    const float s0 = rs[r];
    float4 bv = *(const float4*)(b2 + h0);
    float vx = d.x * s0 + bv.x, vy = d.y * s0 + bv.y;
    float vz = d.z * s0 + bv.z, vw = d.w * s0 + bv.w;

    float ss = vx*vx + vy*vy + vz*vz + vw*vw;
    #pragma unroll
    for (int o2 = 32; o2 > 0; o2 >>= 1) ss += __shfl_xor(ss, o2, 64);
    const float sc = rsqrtf(ss * (1.0f / Hn) + EPSF);

    *(uint2*)&ls[wid][h0] = pack4h(vx*sc, vy*sc, vz*sc, vw*sc);
    __syncthreads();

    const int h = t;
    u32_t w0  = (u32_t)ls[0][h] | ((u32_t)ls[1][h] << 16);
    u32_t w1v = (u32_t)ls[2][h] | ((u32_t)ls[3][h] << 16);
    const int bb   = r0 >> 9;
    const int tcol = r0 & 511;
    *(uint2*)(BmT + (size_t)bb * Hn * Tn + (size_t)h * Tn + tcol) = make_uint2(w0, w1v);
    __syncthreads();
  }
}

// ---------------------------------------------------------------------------
// K3 bar (x REP): inline a-norm + stream own BmT row, packed relu-add.
// 512 blocks, balanced remap, fused output RMSNorm.
// ---------------------------------------------------------------------------
#define JCHB 32
__global__ __launch_bounds__(256) void k_bar(
    const float* __restrict__ Praw, const float* __restrict__ rs,
    const float* __restrict__ b1,
    const us_t* __restrict__ BmT, us_t* __restrict__ Yb)
{
  __shared__ float red[4];
  const int raw = blockIdx.x;
  const int sel = (raw < 256) ? raw : (511 - raw);
  const int bb  = raw >> 8;
  const int i0  = sel * 2;
  const int h   = threadIdx.x;
  const int rg  = bb * Tn + i0;
  const size_t baseY = (size_t)bb * Tn * Hn;
  const us_t* __restrict__ bt = BmT + (size_t)bb * Hn * Tn + (size_t)h * Tn;

  for (int rep = 0; rep < REP; ++rep) {
    const float b1h = b1[h];
    float v0 = fmaf(Praw[(size_t)rg * 512 + h],       rs[rg],     b1h);
    float v1 = fmaf(Praw[(size_t)(rg + 1) * 512 + h], rs[rg + 1], b1h);
    float ss0 = block_reduce_sum_256(v0 * v0, red);
    float ss1 = block_reduce_sum_256(v1 * v1, red);
    const float av0 = v0 * rsqrtf(ss0 * (1.0f / Hn) + EPSF);
    const float av1 = v1 * rsqrtf(ss1 * (1.0f / Hn) + EPSF);

    const __fp16 a0h = (__fp16)av0;
    const __fp16 a1h = (__fp16)av1;
    h2_t z2;  z2[0]  = (__fp16)0.f; z2[1]  = (__fp16)0.f;
    h2_t a02; a02[0] = a0h;         a02[1] = a0h;
    h2_t a12; a12[0] = a1h;         a12[1] = a1h;
    float sum0 = 0.f, sum1 = 0.f;

    const int nfull = i0 & ~(JCHB - 1);
    short8 c0[4], c1[4];

    #define LOADC(dst, jj) { _Pragma("unroll") \
      for (int q = 0; q < 4; ++q) dst[q] = *(const short8*)(bt + (jj) + q * 8); }
    #define PROCP(buf) { _Pragma("unroll") \
      for (int q = 0; q < 4; ++q) { \
        const h2_t* ph = (const h2_t*)&buf[q]; \
        h2_t p0 = z2, p1 = z2; \
        _Pragma("unroll") \
        for (int w2i = 0; w2i < 4; ++w2i) { \
          h2_t bv2 = ph[w2i]; \
          p0 += __builtin_elementwise_max(a02 + bv2, z2); \
          p1 += __builtin_elementwise_max(a12 + bv2, z2); \
        } \
        sum0 += (float)p0[0] + (float)p0[1]; \
        sum1 += (float)p1[0] + (float)p1[1]; } }

    if (nfull > 0) {
      LOADC(c0, 0);
      int j = 0;
      while (true) {
        const bool m1 = (j + JCHB     < nfull);
        const bool m2 = (j + 2 * JCHB < nfull);
        if (m1) LOADC(c1, j + JCHB);
        PROCP(c0);
        j += JCHB;
        if (!m1) break;
        if (m2) LOADC(c0, j + JCHB);
        PROCP(c1);
        j += JCHB;
        if (!m2) break;
      }
    }
    {
      short8 ct[4];
      LOADC(ct, nfull);
      const int lim = i0 - nfull;
      #pragma unroll
      for (int q = 0; q < 4; ++q)
        #pragma unroll
        for (int e = 0; e < 8; ++e) {
          const int jl = q * 8 + e;
          float bv = h2f((us_t)ct[q][e]);
          sum0 += (jl <= lim)     ? fmaxf((float)a0h + bv, 0.f) : 0.f;
          sum1 += (jl <= lim + 1) ? fmaxf((float)a1h + bv, 0.f) : 0.f;
        }
    }
    #undef LOADC
    #undef PROCP

    {
      float ss = block_reduce_sum_256(sum0 * sum0, red);
      float c  = (float)(i0 + 1);
      float sc = rsqrtf(ss * (1.0f / Hn) + EPSF * c * c);
      Yb[baseY + (size_t)i0 * Hn + h] = f2h(sum0 * sc);
    }
    {
      float ss = block_reduce_sum_256(sum1 * sum1, red);
      float c  = (float)(i0 + 2);
      float sc = rsqrtf(ss * (1.0f / Hn) + EPSF * c * c);
      Yb[baseY + (size_t)(i0 + 1) * Hn + h] = f2h(sum1 * sc);
    }
  }
}

// ---------------------------------------------------------------------------
// K4 out (x REP): out = x + Y @ w3 + b3.  16x16 wave tiles, K=256, LDS-free.
// ---------------------------------------------------------------------------
__global__ __launch_bounds__(256, 4) void k_out(
    const us_t* __restrict__ Yb, const us_t* __restrict__ w3t,
    const float* __restrict__ x, const float* __restrict__ b3,
    float* __restrict__ out)
{
  const int wid = threadIdx.x >> 6, lane = threadIdx.x & 63;
  const int wg = blockIdx.x * 4 + wid;
  const int nt = wg & 63, mt = wg >> 6;
  const int m0 = mt * 16, n0 = nt * 16;
  const int lg = lane >> 4, lr = lane & 15;

  const us_t* ap = Yb  + (size_t)(m0 + lr) * Hn + lg * 8;
  const us_t* bp = w3t + (size_t)(n0 + lr) * Hn + lg * 8;

  for (int rep = 0; rep < REP; ++rep) {
    f16x8 a[8], b[8];
    #pragma unroll
    for (int s = 0; s < 8; ++s) a[s] = *(const f16x8*)(ap + s * 32);
    #pragma unroll
    for (int s = 0; s < 8; ++s) b[s] = *(const f16x8*)(bp + s * 32);

    f32x4 acc = {0.f,0.f,0.f,0.f};
    #pragma unroll
    for (int s = 0; s < 8; ++s) acc = MFMA16(a[s], b[s], acc);

    const int row = m0 + lg * 4;
    const int c = n0 + lr;
    const float bv = b3[c];
    #pragma unroll
    for (int i = 0; i < 4; ++i) {
      const size_t o = (size_t)(row + i) * En + c;
      out[o] = x[o] + acc[i] + bv;
    }
  }
}

// ---------------------------------------------------------------------------
extern "C" void kernel_launch(void* const* d_in, const int* in_sizes, int n_in,
                              void* d_out, int out_size, void* d_ws, size_t ws_size,
                              hipStream_t stream) {
  const float* x  = (const float*)d_in[0];
  const float* w1 = (const float*)d_in[1];
  const float* b1 = (const float*)d_in[2];
  const float* w2 = (const float*)d_in[3];
  const float* b2 = (const float*)d_in[4];
  const float* w3 = (const float*)d_in[5];
  const float* b3 = (const float*)d_in[6];
  float* out = (float*)d_out;

  char* q = (char*)d_ws;
  float* Praw = (float*)q;  q += (size_t)Mtot * 512 * 4;   // 2 MB
  us_t* xb    = (us_t*)q;   q += (size_t)Mtot * En * 2;    // 2 MB
  us_t* w1t   = (us_t*)q;   q += (size_t)Hn * En * 2;
  us_t* w2t   = (us_t*)q;   q += (size_t)Hn * En * 2;
  us_t* w3t   = (us_t*)q;   q += (size_t)En * Hn * 2;
  us_t* BmT   = (us_t*)q;   q += (size_t)Mtot * Hn * 2;
  us_t* Yb    = (us_t*)q;   q += (size_t)Mtot * Hn * 2;
  float* rs   = (float*)q;  q += (size_t)Mtot * 4;

  k_prep<<<1024, 256, 0, stream>>>(x, w1, w2, w3, xb, rs, w1t, w2t, w3t);
  k_gemm<<<2048, 256, 0, stream>>>(xb, w1t, w2t, Praw);
  k_norm<<<256,  256, 0, stream>>>(Praw, rs, b2, BmT);
  k_bar <<<512,  256, 0, stream>>>(Praw, rs, b1, BmT, Yb);
  k_out <<<1024, 256, 0, stream>>>(Yb, w3t, x, b3, out);
}

// Round 19
// 58.962 us; speedup vs baseline: 2.2118x; 2.2118x over previous
//
#include <hip/hip_runtime.h>

#define EPSF 1e-6f
#define Bsz 2
#define Tn  512
#define En  1024
#define Hn  256
#define Mtot (Bsz * Tn)          // 1024 rows
typedef unsigned short us_t;
typedef unsigned int   u32_t;

typedef __attribute__((ext_vector_type(8))) __fp16 f16x8;
typedef __attribute__((ext_vector_type(2))) __fp16 h2_t;
typedef __attribute__((ext_vector_type(8))) short  short8;   // raw 16B container
typedef __attribute__((ext_vector_type(4))) float  f32x4;
#define MFMA16(a, b, c) __builtin_amdgcn_mfma_f32_16x16x32_f16((a), (b), (c), 0, 0, 0)

// async global->LDS, 16B per lane, HW appends lane*16 to the uniform LDS base
#define GLOAD_LDS16(g, l) __builtin_amdgcn_global_load_lds( \
  (const __attribute__((address_space(1))) unsigned int*)(g), \
  (__attribute__((address_space(3))) unsigned int*)(l), 16, 0, 0)

// ---------------------------------------------------------------------------
__device__ __forceinline__ us_t f2h(float f) {
  __fp16 h = (__fp16)f;                       // RNE
  return __builtin_bit_cast(us_t, h);
}
__device__ __forceinline__ float h2f(us_t u) {
  return (float)__builtin_bit_cast(__fp16, u);
}
__device__ __forceinline__ uint2 pack4h(float a, float b, float c, float d) {
  uint2 r;
  r.x = (u32_t)f2h(a) | ((u32_t)f2h(b) << 16);
  r.y = (u32_t)f2h(c) | ((u32_t)f2h(d) << 16);
  return r;
}
__device__ __forceinline__ float block_reduce_sum_256(float v, float* smem) {
  #pragma unroll
  for (int off = 32; off > 0; off >>= 1) v += __shfl_down(v, off, 64);
  const int wave = threadIdx.x >> 6;
  if ((threadIdx.x & 63) == 0) smem[wave] = v;
  __syncthreads();
  float s = smem[0] + smem[1] + smem[2] + smem[3];
  __syncthreads();
  return s;
}

// ---------------------------------------------------------------------------
// K0 prep: blocks 0..255: rowscale rs ONLY (xb eliminated — gemm reads x).
//          blocks 256..1023: transpose+cast one 32x32 tile of w1/w2/w3.
// ---------------------------------------------------------------------------
__global__ __launch_bounds__(256) void k_prep(
    const float* __restrict__ x,
    const float* __restrict__ w1, const float* __restrict__ w2,
    const float* __restrict__ w3,
    float* __restrict__ rs,
    us_t* __restrict__ w1t, us_t* __restrict__ w2t, us_t* __restrict__ w3t)
{
  const int b = blockIdx.x, t = threadIdx.x;

  if (b < 256) {
    const int wid = t >> 6, lane = t & 63;
    const int row = b * 4 + wid;
    const float4* xp = (const float4*)(x + (size_t)row * En);
    float ss = 0.f;
    #pragma unroll
    for (int i = 0; i < 4; ++i) {
      float4 v = xp[lane + 64 * i];
      ss += v.x*v.x + v.y*v.y + v.z*v.z + v.w*v.w;
    }
    #pragma unroll
    for (int off = 32; off > 0; off >>= 1) ss += __shfl_xor(ss, off, 64);
    if (lane == 0) rs[row] = rsqrtf(ss * (1.0f / En) + EPSF);
    return;
  }

  __shared__ float ts[32][33];
  const int i = b - 256;
  const float* src; us_t* dst; int R, C, tr, tc;
  if (i < 256)      { src = w1; dst = w1t; R = 1024; C = 256;  tr = i >> 3;  tc = i & 7; }
  else if (i < 512) { int k = i - 256; src = w2; dst = w2t; R = 1024; C = 256; tr = k >> 3; tc = k & 7; }
  else              { int k = i - 512; src = w3; dst = w3t; R = 256; C = 1024; tr = k >> 5; tc = k & 31; }

  const int r = t >> 3, c4 = (t & 7) * 4;
  float4 v = *(const float4*)(src + (size_t)(tr * 32 + r) * C + tc * 32 + c4);
  ts[r][c4 + 0] = v.x; ts[r][c4 + 1] = v.y; ts[r][c4 + 2] = v.z; ts[r][c4 + 3] = v.w;
  __syncthreads();
  float o0 = ts[c4 + 0][r], o1 = ts[c4 + 1][r], o2 = ts[c4 + 2][r], o3 = ts[c4 + 3][r];
  *(uint2*)(dst + (size_t)(tc * 32 + r) * R + tr * 32 + c4) = pack4h(o0, o1, o2, o3);
}

// ---------------------------------------------------------------------------
// K1 gemm: 2048 blocks (nt-major).  Block = 16x16 tile, 4 waves = split-K x4.
// A-frags: read x f32 DIRECTLY (16 float4 loads) + in-reg cvt to f16 —
// Praw = raw x . w; downstream kernels apply rs (normalize(x)@w = rs*(x@w)).
// B k-slice: async global_load_lds, pre-swizzled source, swizzled ds_read.
// ---------------------------------------------------------------------------
__global__ __launch_bounds__(256, 4) void k_gemm(
    const float* __restrict__ x,
    const us_t* __restrict__ w1t, const us_t* __restrict__ w2t,
    float* __restrict__ Praw)
{
  __shared__ us_t Bs[4][16][256];      // 32 KB
  __shared__ float cmb[4][16][16];     // 4 KB

  const int blk = blockIdx.x;
  const int mt = blk & 63, nt = blk >> 6;
  const int m0 = mt * 16, n0 = nt * 16;
  const int t = threadIdx.x;
  const int wid = t >> 6, lane = t & 63;
  const int lg = lane >> 4, lr = lane & 15;
  const int k0 = wid * 256;

  // ---- async-stage B k-slice first (fire-and-forget) ----
  const us_t* bbase = (n0 < Hn) ? (w1t + (size_t)n0 * En)
                                : (w2t + (size_t)(n0 - Hn) * En);
  #pragma unroll
  for (int i = 0; i < 8; ++i) {
    const int r   = 2 * i + (lane >> 5);
    const int c2b = ((lane & 31) * 16) ^ ((r & 7) << 4);
    const us_t* g = bbase + (size_t)r * En + k0 + (c2b >> 1);
    GLOAD_LDS16(g, &Bs[wid][2 * i][0]);
  }

  // ---- A fragments: x f32 -> cvt f16 in-reg (16 independent 16B loads) ----
  const float* ap = x + (size_t)(m0 + lr) * En + k0 + lg * 8;
  f16x8 a[8];
  #pragma unroll
  for (int s = 0; s < 8; ++s) {
    float4 u0 = *(const float4*)(ap + s * 32);
    float4 u1 = *(const float4*)(ap + s * 32 + 4);
    f16x8 av;
    av[0] = (__fp16)u0.x; av[1] = (__fp16)u0.y;
    av[2] = (__fp16)u0.z; av[3] = (__fp16)u0.w;
    av[4] = (__fp16)u1.x; av[5] = (__fp16)u1.y;
    av[6] = (__fp16)u1.z; av[7] = (__fp16)u1.w;
    a[s] = av;
  }
  __syncthreads();   // drains global_load_lds + A loads

  // ---- MFMA: B frag via swizzled ds_read_b128 ----
  f32x4 acc = {0.f,0.f,0.f,0.f};
  const us_t* bs = &Bs[wid][0][0];
  #pragma unroll
  for (int s = 0; s < 8; ++s) {
    const int c2 = (lg * 16 + s * 64) ^ ((lr & 7) << 4);
    f16x8 b = *(const f16x8*)(bs + lr * 256 + (c2 >> 1));
    acc = MFMA16(a[s], b, acc);
  }

  // ---- combine split-K, write Praw 16x16 tile ----
  #pragma unroll
  for (int i = 0; i < 4; ++i)
    cmb[wid][lg * 4 + i][lr] = acc[i];
  __syncthreads();

  const int row = t >> 4, col = t & 15;
  float s2 = cmb[0][row][col] + cmb[1][row][col]
           + cmb[2][row][col] + cmb[3][row][col];
  Praw[(size_t)(m0 + row) * 512 + n0 + col] = s2;
}

// ---------------------------------------------------------------------------
// K2 norm: b-half only.  256 blocks, wave-per-row (applies rs);
// LDS transpose-gather -> BmT[h][t] f16.
// ---------------------------------------------------------------------------
__global__ __launch_bounds__(256) void k_norm(
    const float* __restrict__ Praw, const float* __restrict__ rs,
    const float* __restrict__ b2, us_t* __restrict__ BmT)
{
  const int blk = blockIdx.x, t = threadIdx.x;
  const int wid = t >> 6, lane = t & 63;
  const int h0 = lane * 4;

  __shared__ us_t ls[4][256];
  const int mt = blk & 63, sub = blk >> 6;
  const int r0 = 16 * mt + 4 * sub;
  const int r  = r0 + wid;

  float4 d = *(const float4*)(Praw + (size_t)r * 512 + Hn + h0);
  const float s0 = rs[r];
  float4 bv = *(const float4*)(b2 + h0);
  float vx = d.x * s0 + bv.x, vy = d.y * s0 + bv.y;
  float vz = d.z * s0 + bv.z, vw = d.w * s0 + bv.w;

  float ss = vx*vx + vy*vy + vz*vz + vw*vw;
  #pragma unroll
  for (int o2 = 32; o2 > 0; o2 >>= 1) ss += __shfl_xor(ss, o2, 64);
  const float sc = rsqrtf(ss * (1.0f / Hn) + EPSF);

  *(uint2*)&ls[wid][h0] = pack4h(vx*sc, vy*sc, vz*sc, vw*sc);
  __syncthreads();

  const int h = t;
  u32_t w0  = (u32_t)ls[0][h] | ((u32_t)ls[1][h] << 16);
  u32_t w1v = (u32_t)ls[2][h] | ((u32_t)ls[3][h] << 16);
  const int bb   = r0 >> 9;
  const int tcol = r0 & 511;
  *(uint2*)(BmT + (size_t)bb * Hn * Tn + (size_t)h * Tn + tcol) = make_uint2(w0, w1v);
}

// ---------------------------------------------------------------------------
// K3 bar: ITILE=1 -> 1024 blocks (4 blocks/CU, 2x waves vs R17).
// 4-way balanced remap: CU c's rows {c, c+256, 511-c, 255-c} sum constant.
// Inline a-norm (applies rs), stream own BmT row, packed relu-add, fused
// output RMSNorm.
// ---------------------------------------------------------------------------
#define JCHB 32
__global__ __launch_bounds__(256) void k_bar(
    const float* __restrict__ Praw, const float* __restrict__ rs,
    const float* __restrict__ b1,
    const us_t* __restrict__ BmT, us_t* __restrict__ Yb)
{
  __shared__ float red[4];
  const int raw = blockIdx.x;                      // 0..1023
  const int bb  = raw >> 9;                        // batch
  const int i   = (raw < 512) ? raw : (1023 - raw);// row 0..511 (balanced)
  const int h   = threadIdx.x;
  const int rg  = bb * Tn + i;                     // global row
  const size_t baseY = (size_t)bb * Tn * Hn;
  const us_t* __restrict__ bt = BmT + (size_t)bb * Hn * Tn + (size_t)h * Tn;

  // ---- inline a-normalization for row rg ----
  float v0 = fmaf(Praw[(size_t)rg * 512 + h], rs[rg], b1[h]);
  float ss0 = block_reduce_sum_256(v0 * v0, red);
  const float av = v0 * rsqrtf(ss0 * (1.0f / Hn) + EPSF);

  const __fp16 ah = (__fp16)av;
  h2_t z2; z2[0] = (__fp16)0.f; z2[1] = (__fp16)0.f;
  h2_t a2; a2[0] = ah;          a2[1] = ah;
  float sum = 0.f;

  const int nfull = i & ~(JCHB - 1);
  short8 c0[4], c1[4];

  #define LOADC(dst, jj) { _Pragma("unroll") \
    for (int q = 0; q < 4; ++q) dst[q] = *(const short8*)(bt + (jj) + q * 8); }
  #define PROCP(buf) { _Pragma("unroll") \
    for (int q = 0; q < 4; ++q) { \
      const h2_t* ph = (const h2_t*)&buf[q]; \
      h2_t p = z2; \
      _Pragma("unroll") \
      for (int w2i = 0; w2i < 4; ++w2i) \
        p += __builtin_elementwise_max(a2 + ph[w2i], z2); \
      sum += (float)p[0] + (float)p[1]; } }

  if (nfull > 0) {
    LOADC(c0, 0);
    int j = 0;
    while (true) {
      const bool m1 = (j + JCHB     < nfull);
      const bool m2 = (j + 2 * JCHB < nfull);
      if (m1) LOADC(c1, j + JCHB);
      PROCP(c0);
      j += JCHB;
      if (!m1) break;
      if (m2) LOADC(c0, j + JCHB);
      PROCP(c1);
      j += JCHB;
      if (!m2) break;
    }
  }
  { // predicated scalar f32 tail: j in [nfull, nfull+32), in-bounds (<=511)
    short8 ct[4];
    LOADC(ct, nfull);
    const int lim = i - nfull;                    // 0..31
    const float af = (float)ah;
    #pragma unroll
    for (int q = 0; q < 4; ++q)
      #pragma unroll
      for (int e = 0; e < 8; ++e) {
        const int jl = q * 8 + e;
        float bv = h2f((us_t)ct[q][e]);
        sum += (jl <= lim) ? fmaxf(af + bv, 0.f) : 0.f;
      }
  }
  #undef LOADC
  #undef PROCP

  float ssy = block_reduce_sum_256(sum * sum, red);
  const float c = (float)(i + 1);
  const float sc = rsqrtf(ssy * (1.0f / Hn) + EPSF * c * c);
  Yb[baseY + (size_t)i * Hn + h] = f2h(sum * sc);
}

// ---------------------------------------------------------------------------
// K4 out: out = x + Y @ w3 + b3.  16x16 wave tiles, K=256, LDS-free,
// batched fragment loads.  1024 blocks x 4 waves.
// ---------------------------------------------------------------------------
__global__ __launch_bounds__(256, 4) void k_out(
    const us_t* __restrict__ Yb, const us_t* __restrict__ w3t,
    const float* __restrict__ x, const float* __restrict__ b3,
    float* __restrict__ out)
{
  const int wid = threadIdx.x >> 6, lane = threadIdx.x & 63;
  const int wg = blockIdx.x * 4 + wid;
  const int nt = wg & 63, mt = wg >> 6;
  const int m0 = mt * 16, n0 = nt * 16;
  const int lg = lane >> 4, lr = lane & 15;

  const us_t* ap = Yb  + (size_t)(m0 + lr) * Hn + lg * 8;
  const us_t* bp = w3t + (size_t)(n0 + lr) * Hn + lg * 8;

  f16x8 a[8], b[8];
  #pragma unroll
  for (int s = 0; s < 8; ++s) a[s] = *(const f16x8*)(ap + s * 32);
  #pragma unroll
  for (int s = 0; s < 8; ++s) b[s] = *(const f16x8*)(bp + s * 32);

  f32x4 acc = {0.f,0.f,0.f,0.f};
  #pragma unroll
  for (int s = 0; s < 8; ++s) acc = MFMA16(a[s], b[s], acc);

  const int row = m0 + lg * 4;
  const int c = n0 + lr;
  const float bv = b3[c];
  #pragma unroll
  for (int i = 0; i < 4; ++i) {
    const size_t o = (size_t)(row + i) * En + c;
    out[o] = x[o] + acc[i] + bv;
  }
}

// ---------------------------------------------------------------------------
extern "C" void kernel_launch(void* const* d_in, const int* in_sizes, int n_in,
                              void* d_out, int out_size, void* d_ws, size_t ws_size,
                              hipStream_t stream) {
  const float* x  = (const float*)d_in[0];
  const float* w1 = (const float*)d_in[1];
  const float* b1 = (const float*)d_in[2];
  const float* w2 = (const float*)d_in[3];
  const float* b2 = (const float*)d_in[4];
  const float* w3 = (const float*)d_in[5];
  const float* b3 = (const float*)d_in[6];
  float* out = (float*)d_out;

  char* q = (char*)d_ws;
  float* Praw = (float*)q;  q += (size_t)Mtot * 512 * 4;   // 2 MB
  us_t* w1t   = (us_t*)q;   q += (size_t)Hn * En * 2;
  us_t* w2t   = (us_t*)q;   q += (size_t)Hn * En * 2;
  us_t* w3t   = (us_t*)q;   q += (size_t)En * Hn * 2;
  us_t* BmT   = (us_t*)q;   q += (size_t)Mtot * Hn * 2;
  us_t* Yb    = (us_t*)q;   q += (size_t)Mtot * Hn * 2;
  float* rs   = (float*)q;  q += (size_t)Mtot * 4;

  k_prep<<<1024, 256, 0, stream>>>(x, w1, w2, w3, rs, w1t, w2t, w3t);
  k_gemm<<<2048, 256, 0, stream>>>(x, w1t, w2t, Praw);
  k_norm<<<256,  256, 0, stream>>>(Praw, rs, b2, BmT);
  k_bar <<<1024, 256, 0, stream>>>(Praw, rs, b1, BmT, Yb);
  k_out <<<1024, 256, 0, stream>>>(Yb, w3t, x, b3, out);
}

// Round 20
// 52.485 us; speedup vs baseline: 2.4848x; 1.1234x over previous
//
#include <hip/hip_runtime.h>

#define EPSF 1e-6f
#define Bsz 2
#define Tn  512
#define En  1024
#define Hn  256
#define Mtot (Bsz * Tn)          // 1024 rows
typedef unsigned short us_t;
typedef unsigned int   u32_t;

typedef __attribute__((ext_vector_type(8))) __fp16 f16x8;
typedef __attribute__((ext_vector_type(2))) __fp16 h2_t;
typedef __attribute__((ext_vector_type(8))) short  short8;   // raw 16B container
typedef __attribute__((ext_vector_type(4))) float  f32x4;
#define MFMA16(a, b, c) __builtin_amdgcn_mfma_f32_16x16x32_f16((a), (b), (c), 0, 0, 0)

// async global->LDS, 16B per lane, HW appends lane*16 to the uniform LDS base
#define GLOAD_LDS16(g, l) __builtin_amdgcn_global_load_lds( \
  (const __attribute__((address_space(1))) unsigned int*)(g), \
  (__attribute__((address_space(3))) unsigned int*)(l), 16, 0, 0)

// ---------------------------------------------------------------------------
__device__ __forceinline__ us_t f2h(float f) {
  __fp16 h = (__fp16)f;                       // RNE
  return __builtin_bit_cast(us_t, h);
}
__device__ __forceinline__ float h2f(us_t u) {
  return (float)__builtin_bit_cast(__fp16, u);
}
__device__ __forceinline__ uint2 pack4h(float a, float b, float c, float d) {
  uint2 r;
  r.x = (u32_t)f2h(a) | ((u32_t)f2h(b) << 16);
  r.y = (u32_t)f2h(c) | ((u32_t)f2h(d) << 16);
  return r;
}
__device__ __forceinline__ float block_reduce_sum_256(float v, float* smem) {
  #pragma unroll
  for (int off = 32; off > 0; off >>= 1) v += __shfl_down(v, off, 64);
  const int wave = threadIdx.x >> 6;
  if ((threadIdx.x & 63) == 0) smem[wave] = v;
  __syncthreads();
  float s = smem[0] + smem[1] + smem[2] + smem[3];
  __syncthreads();
  return s;
}

// ---------------------------------------------------------------------------
// K0 prep (R17): blocks 0..255: cast 4 x-rows + rowscale (XCD remap).
//                blocks 256..1023: transpose+cast one 32x32 tile of w1/w2/w3.
// ---------------------------------------------------------------------------
__global__ __launch_bounds__(256) void k_prep(
    const float* __restrict__ x,
    const float* __restrict__ w1, const float* __restrict__ w2,
    const float* __restrict__ w3,
    us_t* __restrict__ xb, float* __restrict__ rs,
    us_t* __restrict__ w1t, us_t* __restrict__ w2t, us_t* __restrict__ w3t)
{
  const int b = blockIdx.x, t = threadIdx.x;

  if (b < 256) {
    const int wid = t >> 6, lane = t & 63;
    const int q   = b >> 3;
    const int mt  = (b & 7) + 8 * (q & 7);
    const int row = 16 * mt + 4 * (q >> 3) + wid;
    const float4* xp = (const float4*)(x + (size_t)row * En);
    float4 v[4];
    #pragma unroll
    for (int i = 0; i < 4; ++i) v[i] = xp[lane + 64 * i];
    float ss = 0.f;
    #pragma unroll
    for (int i = 0; i < 4; ++i)
      ss += v[i].x*v[i].x + v[i].y*v[i].y + v[i].z*v[i].z + v[i].w*v[i].w;
    #pragma unroll
    for (int off = 32; off > 0; off >>= 1) ss += __shfl_xor(ss, off, 64);
    if (lane == 0) rs[row] = rsqrtf(ss * (1.0f / En) + EPSF);
    uint2* xo = (uint2*)(xb + (size_t)row * En);
    #pragma unroll
    for (int i = 0; i < 4; ++i)
      xo[lane + 64 * i] = pack4h(v[i].x, v[i].y, v[i].z, v[i].w);
    return;
  }

  __shared__ float ts[32][33];
  const int i = b - 256;
  const float* src; us_t* dst; int R, C, tr, tc;
  if (i < 256)      { src = w1; dst = w1t; R = 1024; C = 256;  tr = i >> 3;  tc = i & 7; }
  else if (i < 512) { int k = i - 256; src = w2; dst = w2t; R = 1024; C = 256; tr = k >> 3; tc = k & 7; }
  else              { int k = i - 512; src = w3; dst = w3t; R = 256; C = 1024; tr = k >> 5; tc = k & 31; }

  const int r = t >> 3, c4 = (t & 7) * 4;
  float4 v = *(const float4*)(src + (size_t)(tr * 32 + r) * C + tc * 32 + c4);
  ts[r][c4 + 0] = v.x; ts[r][c4 + 1] = v.y; ts[r][c4 + 2] = v.z; ts[r][c4 + 3] = v.w;
  __syncthreads();
  float o0 = ts[c4 + 0][r], o1 = ts[c4 + 1][r], o2 = ts[c4 + 2][r], o3 = ts[c4 + 3][r];
  *(uint2*)(dst + (size_t)(tc * 32 + r) * R + tr * 32 + c4) = pack4h(o0, o1, o2, o3);
}

// ---------------------------------------------------------------------------
// K1 gemm (R17): 2048 blocks (nt-major).  Block = 16x16 tile, 4 waves =
// split-K x4.  A-frags from xb f16; B k-slice async global_load_lds with
// pre-swizzled source + swizzled ds_read.  LDS combine -> Praw.
// ---------------------------------------------------------------------------
__global__ __launch_bounds__(256, 4) void k_gemm(
    const us_t* __restrict__ xb,
    const us_t* __restrict__ w1t, const us_t* __restrict__ w2t,
    float* __restrict__ Praw)
{
  __shared__ us_t Bs[4][16][256];      // 32 KB
  __shared__ float cmb[4][16][16];     // 4 KB

  const int blk = blockIdx.x;
  const int mt = blk & 63, nt = blk >> 6;
  const int m0 = mt * 16, n0 = nt * 16;
  const int t = threadIdx.x;
  const int wid = t >> 6, lane = t & 63;
  const int lg = lane >> 4, lr = lane & 15;
  const int k0 = wid * 256;

  // ---- A fragments -> registers (8 independent 16B loads) ----
  const us_t* ap = xb + (size_t)(m0 + lr) * En + k0 + lg * 8;
  f16x8 a[8];
  #pragma unroll
  for (int s = 0; s < 8; ++s) a[s] = *(const f16x8*)(ap + s * 32);

  // ---- async-stage B k-slice (16 rows x 256 cols) into LDS ----
  const us_t* bbase = (n0 < Hn) ? (w1t + (size_t)n0 * En)
                                : (w2t + (size_t)(n0 - Hn) * En);
  #pragma unroll
  for (int i = 0; i < 8; ++i) {
    const int r   = 2 * i + (lane >> 5);
    const int c2b = ((lane & 31) * 16) ^ ((r & 7) << 4);
    const us_t* g = bbase + (size_t)r * En + k0 + (c2b >> 1);
    GLOAD_LDS16(g, &Bs[wid][2 * i][0]);
  }
  __syncthreads();

  // ---- MFMA: B frag via swizzled ds_read_b128 ----
  f32x4 acc = {0.f,0.f,0.f,0.f};
  const us_t* bs = &Bs[wid][0][0];
  #pragma unroll
  for (int s = 0; s < 8; ++s) {
    const int c2 = (lg * 16 + s * 64) ^ ((lr & 7) << 4);
    f16x8 b = *(const f16x8*)(bs + lr * 256 + (c2 >> 1));
    acc = MFMA16(a[s], b, acc);
  }

  // ---- combine split-K, write Praw 16x16 tile ----
  #pragma unroll
  for (int i = 0; i < 4; ++i)
    cmb[wid][lg * 4 + i][lr] = acc[i];
  __syncthreads();

  const int row = t >> 4, col = t & 15;
  float s2 = cmb[0][row][col] + cmb[1][row][col]
           + cmb[2][row][col] + cmb[3][row][col];
  Praw[(size_t)(m0 + row) * 512 + n0 + col] = s2;
}

// ---------------------------------------------------------------------------
// K2 norm (R17): b-half only.  256 blocks, wave-per-row, XCD-remapped;
// LDS transpose-gather -> BmT[h][t] f16.
// ---------------------------------------------------------------------------
__global__ __launch_bounds__(256) void k_norm(
    const float* __restrict__ Praw, const float* __restrict__ rs,
    const float* __restrict__ b2, us_t* __restrict__ BmT)
{
  const int blk = blockIdx.x, t = threadIdx.x;
  const int wid = t >> 6, lane = t & 63;
  const int h0 = lane * 4;

  __shared__ us_t ls[4][256];
  const int mt = blk & 63, sub = blk >> 6;
  const int r0 = 16 * mt + 4 * sub;
  const int r  = r0 + wid;

  float4 d = *(const float4*)(Praw + (size_t)r * 512 + Hn + h0);
  const float s0 = rs[r];
  float4 bv = *(const float4*)(b2 + h0);
  float vx = d.x * s0 + bv.x, vy = d.y * s0 + bv.y;
  float vz = d.z * s0 + bv.z, vw = d.w * s0 + bv.w;

  float ss = vx*vx + vy*vy + vz*vz + vw*vw;
  #pragma unroll
  for (int o2 = 32; o2 > 0; o2 >>= 1) ss += __shfl_xor(ss, o2, 64);
  const float sc = rsqrtf(ss * (1.0f / Hn) + EPSF);

  *(uint2*)&ls[wid][h0] = pack4h(vx*sc, vy*sc, vz*sc, vw*sc);
  __syncthreads();

  const int h = t;
  u32_t w0  = (u32_t)ls[0][h] | ((u32_t)ls[1][h] << 16);
  u32_t w1v = (u32_t)ls[2][h] | ((u32_t)ls[3][h] << 16);
  const int bb   = r0 >> 9;
  const int tcol = r0 & 511;
  *(uint2*)(BmT + (size_t)bb * Hn * Tn + (size_t)h * Tn + tcol) = make_uint2(w0, w1v);
}

// ---------------------------------------------------------------------------
// K3 bar (ONLY change vs R17): ITILE=1 -> 1024 blocks (4 blocks/CU, 2x
// in-flight loads).  4-way balanced remap: CU c's rows {c, c+256, 511-c,
// 255-c} sum constant.  Inline a-norm, stream own BmT row, packed relu-add,
// per-8j f32 flush, fused output RMSNorm.
// ---------------------------------------------------------------------------
#define JCHB 32
__global__ __launch_bounds__(256) void k_bar(
    const float* __restrict__ Praw, const float* __restrict__ rs,
    const float* __restrict__ b1,
    const us_t* __restrict__ BmT, us_t* __restrict__ Yb)
{
  __shared__ float red[4];
  const int raw = blockIdx.x;                      // 0..1023
  const int bb  = raw >> 9;                        // batch
  const int i   = (raw < 512) ? raw : (1023 - raw);// row 0..511 (balanced)
  const int h   = threadIdx.x;
  const int rg  = bb * Tn + i;                     // global row
  const size_t baseY = (size_t)bb * Tn * Hn;
  const us_t* __restrict__ bt = BmT + (size_t)bb * Hn * Tn + (size_t)h * Tn;

  // ---- inline a-normalization for row rg ----
  float v0 = fmaf(Praw[(size_t)rg * 512 + h], rs[rg], b1[h]);
  float ss0 = block_reduce_sum_256(v0 * v0, red);
  const float av = v0 * rsqrtf(ss0 * (1.0f / Hn) + EPSF);

  const __fp16 ah = (__fp16)av;
  h2_t z2; z2[0] = (__fp16)0.f; z2[1] = (__fp16)0.f;
  h2_t a2; a2[0] = ah;          a2[1] = ah;
  float sum = 0.f;

  const int nfull = i & ~(JCHB - 1);
  short8 c0[4], c1[4];

  #define LOADC(dst, jj) { _Pragma("unroll") \
    for (int q = 0; q < 4; ++q) dst[q] = *(const short8*)(bt + (jj) + q * 8); }
  #define PROCP(buf) { _Pragma("unroll") \
    for (int q = 0; q < 4; ++q) { \
      const h2_t* ph = (const h2_t*)&buf[q]; \
      h2_t p = z2; \
      _Pragma("unroll") \
      for (int w2i = 0; w2i < 4; ++w2i) \
        p += __builtin_elementwise_max(a2 + ph[w2i], z2); \
      sum += (float)p[0] + (float)p[1]; } }

  if (nfull > 0) {
    LOADC(c0, 0);
    int j = 0;
    while (true) {
      const bool m1 = (j + JCHB     < nfull);
      const bool m2 = (j + 2 * JCHB < nfull);
      if (m1) LOADC(c1, j + JCHB);
      PROCP(c0);
      j += JCHB;
      if (!m1) break;
      if (m2) LOADC(c0, j + JCHB);
      PROCP(c1);
      j += JCHB;
      if (!m2) break;
    }
  }
  { // predicated scalar f32 tail: j in [nfull, nfull+32), in-bounds (<=511)
    short8 ct[4];
    LOADC(ct, nfull);
    const int lim = i - nfull;                    // 0..31
    const float af = (float)ah;
    #pragma unroll
    for (int q = 0; q < 4; ++q)
      #pragma unroll
      for (int e = 0; e < 8; ++e) {
        const int jl = q * 8 + e;
        float bv = h2f((us_t)ct[q][e]);
        sum += (jl <= lim) ? fmaxf(af + bv, 0.f) : 0.f;
      }
  }
  #undef LOADC
  #undef PROCP

  float ssy = block_reduce_sum_256(sum * sum, red);
  const float c = (float)(i + 1);
  const float sc = rsqrtf(ssy * (1.0f / Hn) + EPSF * c * c);
  Yb[baseY + (size_t)i * Hn + h] = f2h(sum * sc);
}

// ---------------------------------------------------------------------------
// K4 out (R17): out = x + Y @ w3 + b3.  16x16 wave tiles, K=256, LDS-free,
// batched fragment loads.  1024 blocks x 4 waves.
// ---------------------------------------------------------------------------
__global__ __launch_bounds__(256, 4) void k_out(
    const us_t* __restrict__ Yb, const us_t* __restrict__ w3t,
    const float* __restrict__ x, const float* __restrict__ b3,
    float* __restrict__ out)
{
  const int wid = threadIdx.x >> 6, lane = threadIdx.x & 63;
  const int wg = blockIdx.x * 4 + wid;
  const int nt = wg & 63, mt = wg >> 6;
  const int m0 = mt * 16, n0 = nt * 16;
  const int lg = lane >> 4, lr = lane & 15;

  const us_t* ap = Yb  + (size_t)(m0 + lr) * Hn + lg * 8;
  const us_t* bp = w3t + (size_t)(n0 + lr) * Hn + lg * 8;

  f16x8 a[8], b[8];
  #pragma unroll
  for (int s = 0; s < 8; ++s) a[s] = *(const f16x8*)(ap + s * 32);
  #pragma unroll
  for (int s = 0; s < 8; ++s) b[s] = *(const f16x8*)(bp + s * 32);

  f32x4 acc = {0.f,0.f,0.f,0.f};
  #pragma unroll
  for (int s = 0; s < 8; ++s) acc = MFMA16(a[s], b[s], acc);

  const int row = m0 + lg * 4;
  const int c = n0 + lr;
  const float bv = b3[c];
  #pragma unroll
  for (int i = 0; i < 4; ++i) {
    const size_t o = (size_t)(row + i) * En + c;
    out[o] = x[o] + acc[i] + bv;
  }
}

// ---------------------------------------------------------------------------
extern "C" void kernel_launch(void* const* d_in, const int* in_sizes, int n_in,
                              void* d_out, int out_size, void* d_ws, size_t ws_size,
                              hipStream_t stream) {
  const float* x  = (const float*)d_in[0];
  const float* w1 = (const float*)d_in[1];
  const float* b1 = (const float*)d_in[2];
  const float* w2 = (const float*)d_in[3];
  const float* b2 = (const float*)d_in[4];
  const float* w3 = (const float*)d_in[5];
  const float* b3 = (const float*)d_in[6];
  float* out = (float*)d_out;

  char* q = (char*)d_ws;
  float* Praw = (float*)q;  q += (size_t)Mtot * 512 * 4;   // 2 MB
  us_t* xb    = (us_t*)q;   q += (size_t)Mtot * En * 2;    // 2 MB
  us_t* w1t   = (us_t*)q;   q += (size_t)Hn * En * 2;
  us_t* w2t   = (us_t*)q;   q += (size_t)Hn * En * 2;
  us_t* w3t   = (us_t*)q;   q += (size_t)En * Hn * 2;
  us_t* BmT   = (us_t*)q;   q += (size_t)Mtot * Hn * 2;
  us_t* Yb    = (us_t*)q;   q += (size_t)Mtot * Hn * 2;
  float* rs   = (float*)q;  q += (size_t)Mtot * 4;

  k_prep<<<1024, 256, 0, stream>>>(x, w1, w2, w3, xb, rs, w1t, w2t, w3t);
  k_gemm<<<2048, 256, 0, stream>>>(xb, w1t, w2t, Praw);
  k_norm<<<256,  256, 0, stream>>>(Praw, rs, b2, BmT);
  k_bar <<<1024, 256, 0, stream>>>(Praw, rs, b1, BmT, Yb);
  k_out <<<1024, 256, 0, stream>>>(Yb, w3t, x, b3, out);
}

// Round 21
// 46.325 us; speedup vs baseline: 2.8152x; 1.1330x over previous
//
#include <hip/hip_runtime.h>

#define EPSF 1e-6f
#define Bsz 2
#define Tn  512
#define En  1024
#define Hn  256
#define Mtot (Bsz * Tn)          // 1024 rows
typedef unsigned short us_t;
typedef unsigned int   u32_t;

typedef __attribute__((ext_vector_type(8))) __fp16 f16x8;
typedef __attribute__((ext_vector_type(2))) __fp16 h2_t;
typedef __attribute__((ext_vector_type(8))) short  short8;   // raw 16B container
typedef __attribute__((ext_vector_type(4))) float  f32x4;
#define MFMA16(a, b, c) __builtin_amdgcn_mfma_f32_16x16x32_f16((a), (b), (c), 0, 0, 0)

// async global->LDS, 16B per lane, HW appends lane*16 to the uniform LDS base
#define GLOAD_LDS16(g, l) __builtin_amdgcn_global_load_lds( \
  (const __attribute__((address_space(1))) unsigned int*)(g), \
  (__attribute__((address_space(3))) unsigned int*)(l), 16, 0, 0)

// ---------------------------------------------------------------------------
__device__ __forceinline__ us_t f2h(float f) {
  __fp16 h = (__fp16)f;                       // RNE
  return __builtin_bit_cast(us_t, h);
}
__device__ __forceinline__ float h2f(us_t u) {
  return (float)__builtin_bit_cast(__fp16, u);
}
__device__ __forceinline__ uint2 pack4h(float a, float b, float c, float d) {
  uint2 r;
  r.x = (u32_t)f2h(a) | ((u32_t)f2h(b) << 16);
  r.y = (u32_t)f2h(c) | ((u32_t)f2h(d) << 16);
  return r;
}
__device__ __forceinline__ float block_reduce_sum_256(float v, float* smem) {
  #pragma unroll
  for (int off = 32; off > 0; off >>= 1) v += __shfl_down(v, off, 64);
  const int wave = threadIdx.x >> 6;
  if ((threadIdx.x & 63) == 0) smem[wave] = v;
  __syncthreads();
  float s = smem[0] + smem[1] + smem[2] + smem[3];
  __syncthreads();
  return s;
}
// 512-thread block reduce (threads contributing 0 still participate)
__device__ __forceinline__ float block_reduce_sum_512(float v, float* smem) {
  #pragma unroll
  for (int off = 32; off > 0; off >>= 1) v += __shfl_down(v, off, 64);
  const int wave = threadIdx.x >> 6;
  if ((threadIdx.x & 63) == 0) smem[wave] = v;
  __syncthreads();
  float s = smem[0] + smem[1] + smem[2] + smem[3]
          + smem[4] + smem[5] + smem[6] + smem[7];
  __syncthreads();
  return s;
}

// ---------------------------------------------------------------------------
// K0 prep (R17): blocks 0..255: cast 4 x-rows + rowscale (XCD remap).
//                blocks 256..1023: transpose+cast one 32x32 tile of w1/w2/w3.
// ---------------------------------------------------------------------------
__global__ __launch_bounds__(256) void k_prep(
    const float* __restrict__ x,
    const float* __restrict__ w1, const float* __restrict__ w2,
    const float* __restrict__ w3,
    us_t* __restrict__ xb, float* __restrict__ rs,
    us_t* __restrict__ w1t, us_t* __restrict__ w2t, us_t* __restrict__ w3t)
{
  const int b = blockIdx.x, t = threadIdx.x;

  if (b < 256) {
    const int wid = t >> 6, lane = t & 63;
    const int q   = b >> 3;
    const int mt  = (b & 7) + 8 * (q & 7);
    const int row = 16 * mt + 4 * (q >> 3) + wid;
    const float4* xp = (const float4*)(x + (size_t)row * En);
    float4 v[4];
    #pragma unroll
    for (int i = 0; i < 4; ++i) v[i] = xp[lane + 64 * i];
    float ss = 0.f;
    #pragma unroll
    for (int i = 0; i < 4; ++i)
      ss += v[i].x*v[i].x + v[i].y*v[i].y + v[i].z*v[i].z + v[i].w*v[i].w;
    #pragma unroll
    for (int off = 32; off > 0; off >>= 1) ss += __shfl_xor(ss, off, 64);
    if (lane == 0) rs[row] = rsqrtf(ss * (1.0f / En) + EPSF);
    uint2* xo = (uint2*)(xb + (size_t)row * En);
    #pragma unroll
    for (int i = 0; i < 4; ++i)
      xo[lane + 64 * i] = pack4h(v[i].x, v[i].y, v[i].z, v[i].w);
    return;
  }

  __shared__ float ts[32][33];
  const int i = b - 256;
  const float* src; us_t* dst; int R, C, tr, tc;
  if (i < 256)      { src = w1; dst = w1t; R = 1024; C = 256;  tr = i >> 3;  tc = i & 7; }
  else if (i < 512) { int k = i - 256; src = w2; dst = w2t; R = 1024; C = 256; tr = k >> 3; tc = k & 7; }
  else              { int k = i - 512; src = w3; dst = w3t; R = 256; C = 1024; tr = k >> 5; tc = k & 31; }

  const int r = t >> 3, c4 = (t & 7) * 4;
  float4 v = *(const float4*)(src + (size_t)(tr * 32 + r) * C + tc * 32 + c4);
  ts[r][c4 + 0] = v.x; ts[r][c4 + 1] = v.y; ts[r][c4 + 2] = v.z; ts[r][c4 + 3] = v.w;
  __syncthreads();
  float o0 = ts[c4 + 0][r], o1 = ts[c4 + 1][r], o2 = ts[c4 + 2][r], o3 = ts[c4 + 3][r];
  *(uint2*)(dst + (size_t)(tc * 32 + r) * R + tr * 32 + c4) = pack4h(o0, o1, o2, o3);
}

// ---------------------------------------------------------------------------
// K1 gemm (R17): 2048 blocks (nt-major).  Block = 16x16 tile, 4 waves =
// split-K x4.  A-frags from xb f16; B k-slice async global_load_lds with
// pre-swizzled source + swizzled ds_read.  LDS combine -> Praw.
// ---------------------------------------------------------------------------
__global__ __launch_bounds__(256, 4) void k_gemm(
    const us_t* __restrict__ xb,
    const us_t* __restrict__ w1t, const us_t* __restrict__ w2t,
    float* __restrict__ Praw)
{
  __shared__ us_t Bs[4][16][256];      // 32 KB
  __shared__ float cmb[4][16][16];     // 4 KB

  const int blk = blockIdx.x;
  const int mt = blk & 63, nt = blk >> 6;
  const int m0 = mt * 16, n0 = nt * 16;
  const int t = threadIdx.x;
  const int wid = t >> 6, lane = t & 63;
  const int lg = lane >> 4, lr = lane & 15;
  const int k0 = wid * 256;

  // ---- A fragments -> registers (8 independent 16B loads) ----
  const us_t* ap = xb + (size_t)(m0 + lr) * En + k0 + lg * 8;
  f16x8 a[8];
  #pragma unroll
  for (int s = 0; s < 8; ++s) a[s] = *(const f16x8*)(ap + s * 32);

  // ---- async-stage B k-slice (16 rows x 256 cols) into LDS ----
  const us_t* bbase = (n0 < Hn) ? (w1t + (size_t)n0 * En)
                                : (w2t + (size_t)(n0 - Hn) * En);
  #pragma unroll
  for (int i = 0; i < 8; ++i) {
    const int r   = 2 * i + (lane >> 5);
    const int c2b = ((lane & 31) * 16) ^ ((r & 7) << 4);
    const us_t* g = bbase + (size_t)r * En + k0 + (c2b >> 1);
    GLOAD_LDS16(g, &Bs[wid][2 * i][0]);
  }
  __syncthreads();

  // ---- MFMA: B frag via swizzled ds_read_b128 ----
  f32x4 acc = {0.f,0.f,0.f,0.f};
  const us_t* bs = &Bs[wid][0][0];
  #pragma unroll
  for (int s = 0; s < 8; ++s) {
    const int c2 = (lg * 16 + s * 64) ^ ((lr & 7) << 4);
    f16x8 b = *(const f16x8*)(bs + lr * 256 + (c2 >> 1));
    acc = MFMA16(a[s], b, acc);
  }

  // ---- combine split-K, write Praw 16x16 tile ----
  #pragma unroll
  for (int i = 0; i < 4; ++i)
    cmb[wid][lg * 4 + i][lr] = acc[i];
  __syncthreads();

  const int row = t >> 4, col = t & 15;
  float s2 = cmb[0][row][col] + cmb[1][row][col]
           + cmb[2][row][col] + cmb[3][row][col];
  Praw[(size_t)(m0 + row) * 512 + n0 + col] = s2;
}

// ---------------------------------------------------------------------------
// K2 norm (R17): b-half only.  256 blocks, wave-per-row, XCD-remapped;
// LDS transpose-gather -> BmT[h][t] f16.
// ---------------------------------------------------------------------------
__global__ __launch_bounds__(256) void k_norm(
    const float* __restrict__ Praw, const float* __restrict__ rs,
    const float* __restrict__ b2, us_t* __restrict__ BmT)
{
  const int blk = blockIdx.x, t = threadIdx.x;
  const int wid = t >> 6, lane = t & 63;
  const int h0 = lane * 4;

  __shared__ us_t ls[4][256];
  const int mt = blk & 63, sub = blk >> 6;
  const int r0 = 16 * mt + 4 * sub;
  const int r  = r0 + wid;

  float4 d = *(const float4*)(Praw + (size_t)r * 512 + Hn + h0);
  const float s0 = rs[r];
  float4 bv = *(const float4*)(b2 + h0);
  float vx = d.x * s0 + bv.x, vy = d.y * s0 + bv.y;
  float vz = d.z * s0 + bv.z, vw = d.w * s0 + bv.w;

  float ss = vx*vx + vy*vy + vz*vz + vw*vw;
  #pragma unroll
  for (int o2 = 32; o2 > 0; o2 >>= 1) ss += __shfl_xor(ss, o2, 64);
  const float sc = rsqrtf(ss * (1.0f / Hn) + EPSF);

  *(uint2*)&ls[wid][h0] = pack4h(vx*sc, vy*sc, vz*sc, vw*sc);
  __syncthreads();

  const int h = t;
  u32_t w0  = (u32_t)ls[0][h] | ((u32_t)ls[1][h] << 16);
  u32_t w1v = (u32_t)ls[2][h] | ((u32_t)ls[3][h] << 16);
  const int bb   = r0 >> 9;
  const int tcol = r0 & 511;
  *(uint2*)(BmT + (size_t)bb * Hn * Tn + (size_t)h * Tn + tcol) = make_uint2(w0, w1v);
}

// ---------------------------------------------------------------------------
// K3 bar (ONLY change vs R17): 512 threads/block, ITILE=2, 512 blocks.
// Thread (h = t&255, jh = t>>8): jh takes alternating 32-j chunks — halves
// each thread's serialized load chain at UNCHANGED BmT traffic.  LDS partial
// combine; inline a-norm (jh-masked 512-reduce); fused output RMSNorm.
// ---------------------------------------------------------------------------
#define JCHB 32
__global__ __launch_bounds__(512) void k_bar(
    const float* __restrict__ Praw, const float* __restrict__ rs,
    const float* __restrict__ b1,
    const us_t* __restrict__ BmT, us_t* __restrict__ Yb)
{
  __shared__ float red[8];
  __shared__ float part0[2][256], part1[2][256];

  const int raw = blockIdx.x;
  const int sel = (raw < 256) ? raw : (511 - raw);
  const int bb  = raw >> 8;
  const int i0  = sel * 2;
  const int t   = threadIdx.x;
  const int h   = t & 255, jh = t >> 8;
  const int rg  = bb * Tn + i0;
  const size_t baseY = (size_t)bb * Tn * Hn;
  const us_t* __restrict__ bt = BmT + (size_t)bb * Hn * Tn + (size_t)h * Tn;

  // ---- inline a-normalization for rows rg, rg+1 (jh-masked reduce) ----
  const float b1h = b1[h];
  float v0 = fmaf(Praw[(size_t)rg * 512 + h],       rs[rg],     b1h);
  float v1 = fmaf(Praw[(size_t)(rg + 1) * 512 + h], rs[rg + 1], b1h);
  float ss0 = block_reduce_sum_512((jh == 0) ? v0 * v0 : 0.f, red);
  float ss1 = block_reduce_sum_512((jh == 0) ? v1 * v1 : 0.f, red);
  const float av0 = v0 * rsqrtf(ss0 * (1.0f / Hn) + EPSF);
  const float av1 = v1 * rsqrtf(ss1 * (1.0f / Hn) + EPSF);

  const __fp16 a0h = (__fp16)av0;
  const __fp16 a1h = (__fp16)av1;
  h2_t z2;  z2[0]  = (__fp16)0.f; z2[1]  = (__fp16)0.f;
  h2_t a02; a02[0] = a0h;         a02[1] = a0h;
  h2_t a12; a12[0] = a1h;         a12[1] = a1h;
  float sum0 = 0.f, sum1 = 0.f;

  const int nch = i0 >> 5;          // number of full 32-j chunks
  short8 c0v[4], c1v[4];

  #define LOADC(dst, jj) { _Pragma("unroll") \
    for (int q = 0; q < 4; ++q) dst[q] = *(const short8*)(bt + (jj) + q * 8); }
  #define PROCP(buf) { _Pragma("unroll") \
    for (int q = 0; q < 4; ++q) { \
      const h2_t* ph = (const h2_t*)&buf[q]; \
      h2_t p0 = z2, p1 = z2; \
      _Pragma("unroll") \
      for (int w2i = 0; w2i < 4; ++w2i) { \
        h2_t bv2 = ph[w2i]; \
        p0 += __builtin_elementwise_max(a02 + bv2, z2); \
        p1 += __builtin_elementwise_max(a12 + bv2, z2); \
      } \
      sum0 += (float)p0[0] + (float)p0[1]; \
      sum1 += (float)p1[0] + (float)p1[1]; } }

  // jh processes chunks ch = jh, jh+2, ... < nch (double-buffered)
  int ch = jh;
  if (ch < nch) {
    LOADC(c0v, ch * JCHB);
    while (true) {
      int nx = ch + 2;
      bool more = (nx < nch);
      if (more) LOADC(c1v, nx * JCHB);
      PROCP(c0v);
      ch = nx;
      if (!more) break;
      nx = ch + 2;
      more = (nx < nch);
      if (more) LOADC(c0v, nx * JCHB);
      PROCP(c1v);
      ch = nx;
      if (!more) break;
    }
  }
  // predicated tail chunk j in [nch*32, i0+2): owner jh == (nch&1) (balance)
  if (jh == (nch & 1)) {
    short8 ct[4];
    LOADC(ct, nch * JCHB);
    const int lim = i0 - nch * JCHB;        // 0..30
    const float af0 = (float)a0h, af1 = (float)a1h;
    #pragma unroll
    for (int q = 0; q < 4; ++q)
      #pragma unroll
      for (int e = 0; e < 8; ++e) {
        const int jl = q * 8 + e;
        float bv = h2f((us_t)ct[q][e]);
        sum0 += (jl <= lim)     ? fmaxf(af0 + bv, 0.f) : 0.f;
        sum1 += (jl <= lim + 1) ? fmaxf(af1 + bv, 0.f) : 0.f;
      }
  }
  #undef LOADC
  #undef PROCP

  part0[jh][h] = sum0;
  part1[jh][h] = sum1;
  __syncthreads();

  const float tot0 = part0[0][h] + part0[1][h];
  const float tot1 = part1[0][h] + part1[1][h];

  float ssy0 = block_reduce_sum_512((jh == 0) ? tot0 * tot0 : 0.f, red);
  float ssy1 = block_reduce_sum_512((jh == 0) ? tot1 * tot1 : 0.f, red);

  if (jh == 0) {
    float cA = (float)(i0 + 1);
    float scA = rsqrtf(ssy0 * (1.0f / Hn) + EPSF * cA * cA);
    Yb[baseY + (size_t)i0 * Hn + h] = f2h(tot0 * scA);
    float cB = (float)(i0 + 2);
    float scB = rsqrtf(ssy1 * (1.0f / Hn) + EPSF * cB * cB);
    Yb[baseY + (size_t)(i0 + 1) * Hn + h] = f2h(tot1 * scB);
  }
}

// ---------------------------------------------------------------------------
// K4 out (R17): out = x + Y @ w3 + b3.  16x16 wave tiles, K=256, LDS-free,
// batched fragment loads.  1024 blocks x 4 waves.
// ---------------------------------------------------------------------------
__global__ __launch_bounds__(256, 4) void k_out(
    const us_t* __restrict__ Yb, const us_t* __restrict__ w3t,
    const float* __restrict__ x, const float* __restrict__ b3,
    float* __restrict__ out)
{
  const int wid = threadIdx.x >> 6, lane = threadIdx.x & 63;
  const int wg = blockIdx.x * 4 + wid;
  const int nt = wg & 63, mt = wg >> 6;
  const int m0 = mt * 16, n0 = nt * 16;
  const int lg = lane >> 4, lr = lane & 15;

  const us_t* ap = Yb  + (size_t)(m0 + lr) * Hn + lg * 8;
  const us_t* bp = w3t + (size_t)(n0 + lr) * Hn + lg * 8;

  f16x8 a[8], b[8];
  #pragma unroll
  for (int s = 0; s < 8; ++s) a[s] = *(const f16x8*)(ap + s * 32);
  #pragma unroll
  for (int s = 0; s < 8; ++s) b[s] = *(const f16x8*)(bp + s * 32);

  f32x4 acc = {0.f,0.f,0.f,0.f};
  #pragma unroll
  for (int s = 0; s < 8; ++s) acc = MFMA16(a[s], b[s], acc);

  const int row = m0 + lg * 4;
  const int c = n0 + lr;
  const float bv = b3[c];
  #pragma unroll
  for (int i = 0; i < 4; ++i) {
    const size_t o = (size_t)(row + i) * En + c;
    out[o] = x[o] + acc[i] + bv;
  }
}

// ---------------------------------------------------------------------------
extern "C" void kernel_launch(void* const* d_in, const int* in_sizes, int n_in,
                              void* d_out, int out_size, void* d_ws, size_t ws_size,
                              hipStream_t stream) {
  const float* x  = (const float*)d_in[0];
  const float* w1 = (const float*)d_in[1];
  const float* b1 = (const float*)d_in[2];
  const float* w2 = (const float*)d_in[3];
  const float* b2 = (const float*)d_in[4];
  const float* w3 = (const float*)d_in[5];
  const float* b3 = (const float*)d_in[6];
  float* out = (float*)d_out;

  char* q = (char*)d_ws;
  float* Praw = (float*)q;  q += (size_t)Mtot * 512 * 4;   // 2 MB
  us_t* xb    = (us_t*)q;   q += (size_t)Mtot * En * 2;    // 2 MB
  us_t* w1t   = (us_t*)q;   q += (size_t)Hn * En * 2;
  us_t* w2t   = (us_t*)q;   q += (size_t)Hn * En * 2;
  us_t* w3t   = (us_t*)q;   q += (size_t)En * Hn * 2;
  us_t* BmT   = (us_t*)q;   q += (size_t)Mtot * Hn * 2;
  us_t* Yb    = (us_t*)q;   q += (size_t)Mtot * Hn * 2;
  float* rs   = (float*)q;  q += (size_t)Mtot * 4;

  k_prep<<<1024, 256, 0, stream>>>(x, w1, w2, w3, xb, rs, w1t, w2t, w3t);
  k_gemm<<<2048, 256, 0, stream>>>(xb, w1t, w2t, Praw);
  k_norm<<<256,  256, 0, stream>>>(Praw, rs, b2, BmT);
  k_bar <<<512,  512, 0, stream>>>(Praw, rs, b1, BmT, Yb);
  k_out <<<1024, 256, 0, stream>>>(Yb, w3t, x, b3, out);
}